// Round 1
// baseline (7079.482 us; speedup 1.0000x reference)
//
#include <hip/hip_runtime.h>

// IterativeGatedConv2D: 8 iterations of
//   g  = circ_depthwise_conv7x7(h, Wg)
//   ht = circ_depthwise_conv7x7(h, Wh)
//   h  = h + sigmoid(g) * (ht - h)
//
// Layout: (B=8, H=256, W=256, C=64) channels-last fp32.
// Block: 256 threads = 64 channels (lane c = tid&63) x 4 x-positions (xi = tid>>6).
// Each thread computes TH=8 outputs along y. LDS tile (8+6)x(4+6)x64 fp32.
//
// R4: TWO-PASS conv to kill AGPR spill traffic.
//   R1-R3 kept 98 weights + 16 accs live (~135 regs) -> allocator parked
//   weights in AGPRs (VGPR_Count=84, unified-file ~148) -> every FMA paid an
//   extra v_accvgpr_read: ~4400 VALU cyc/wave vs 1568 of real FMA, occupancy
//   capped at 3 waves/SIMD. Fix: pass 1 = gate conv (49 weights) -> z[8];
//   sched_barrier(0); pass 2 reloads the same 49 regs with hidden weights and
//   re-reads the unchanged LDS tile. Max live ~95 regs -> fits the 128-reg cap
//   of __launch_bounds__(256,4) with zero spills; 4 blocks/CU (LDS 4x35KB).
// R4b: XCD-aware remap of a flattened 1D grid (16384 blocks, %8==0, bijective):
//   batch image b = id&7 stays on one XCD -> halo overlap (tile 14x10 vs 8x4
//   useful) resolves in that XCD's L2 instead of HBM refetch.

#define HH 256
#define WW 256
#define CC 64
#define TH 8
#define TW 4
#define LH (TH + 6) // 14
#define LW (TW + 6) // 10

__global__ __launch_bounds__(256, 4) void gated_step(
    const float* __restrict__ src,
    const float* __restrict__ wg_g,
    const float* __restrict__ wh_g,
    float* __restrict__ dst)
{
    __shared__ float tile[LH * LW * CC]; // 35840 B

    const int tid = threadIdx.x;
    const int c   = tid & 63;
    const int xi  = tid >> 6;      // 0..3

    // XCD-aware remap: flattened id -> (bx, by, b). 2048 blocks = one batch
    // image per XCD (assuming round-robin id->XCD); row-major sweep within.
    const int id  = (int)blockIdx.x;
    const int nid = ((id & 7) << 11) | (id >> 3);
    const int bx  = nid & 63;
    const int by  = (nid >> 6) & 31;
    const int b   = nid >> 11;     // == id & 7

    const int x0  = bx * TW;
    const int y0  = by * TH;

    // ---- stage input tile with circular wrap, float4-vectorized ----
    const float4* __restrict__ src4 = reinterpret_cast<const float4*>(src);
    const int total4 = LH * LW * (CC / 4); // 2240
    for (int k = tid; k < total4; k += 256) {
        int c4 = k & 15;
        int sp = k >> 4;              // 0..139
        int jx = sp % LW;
        int iy = sp / LW;
        int gy = (y0 + iy - 3) & 255;
        int gx = (x0 + jx - 3) & 255;
        float4 val = src4[(((b << 8) + gy) << 8 | gx) * (CC / 4) + c4];
        *reinterpret_cast<float4*>(&tile[(sp << 6) + (c4 << 2)]) = val;
    }
    __syncthreads();

    const float* tbase = &tile[xi * CC + c];

    // ================= pass 1: gate conv (49 weights live) =================
    float w[49];
    #pragma unroll
    for (int t = 0; t < 49; ++t) w[t] = wg_g[c * 49 + t];

    float acc[TH];
    #pragma unroll
    for (int r = 0; r < TH; ++r) acc[r] = 0.0f;

    #pragma unroll
    for (int iy = 0; iy < LH; ++iy) {
        float v[7];
        #pragma unroll
        for (int jv = 0; jv < 7; ++jv)
            v[jv] = tbase[(iy * LW + jv) * CC];
        #pragma unroll
        for (int r = 0; r < TH; ++r) {
            const int i = r + 6 - iy;   // kernel row index
            if (i >= 0 && i <= 6) {
                #pragma unroll
                for (int jv = 0; jv < 7; ++jv)
                    acc[r] = fmaf(w[i * 7 + (6 - jv)], v[jv], acc[r]);
            }
        }
    }

    float z[TH];
    #pragma unroll
    for (int r = 0; r < TH; ++r) {
        float e = __expf(-acc[r]);
        z[r] = __builtin_amdgcn_rcpf(1.0f + e);
    }

    // Keep pass-2 weight loads BELOW pass 1 so the 2x49 weights are never
    // simultaneously live (that's what re-created the AGPR spills).
    __builtin_amdgcn_sched_barrier(0);

    // ================= pass 2: hidden conv (reuse w[]) =====================
    #pragma unroll
    for (int t = 0; t < 49; ++t) w[t] = wh_g[c * 49 + t];

    float ctr[TH];
    #pragma unroll
    for (int r = 0; r < TH; ++r) acc[r] = 0.0f;

    #pragma unroll
    for (int iy = 0; iy < LH; ++iy) {
        float v[7];
        #pragma unroll
        for (int jv = 0; jv < 7; ++jv)
            v[jv] = tbase[(iy * LW + jv) * CC];
        if (iy >= 3 && iy < 3 + TH) ctr[iy - 3] = v[3]; // center tap = h itself
        #pragma unroll
        for (int r = 0; r < TH; ++r) {
            const int i = r + 6 - iy;
            if (i >= 0 && i <= 6) {
                #pragma unroll
                for (int jv = 0; jv < 7; ++jv)
                    acc[r] = fmaf(w[i * 7 + (6 - jv)], v[jv], acc[r]);
            }
        }
    }

    // ---- epilogue: blend with pass-1 gate, coalesced store ----
    #pragma unroll
    for (int r = 0; r < TH; ++r) {
        float hn = fmaf(z[r], acc[r] - ctr[r], ctr[r]);
        int gy = y0 + r;
        int gx = x0 + xi;
        dst[((((b << 8) + gy) << 8) + gx) * CC + c] = hn;
    }
}

extern "C" void kernel_launch(void* const* d_in, const int* in_sizes, int n_in,
                              void* d_out, int out_size, void* d_ws, size_t ws_size,
                              hipStream_t stream) {
    const float* x  = (const float*)d_in[0];
    const float* wg = (const float*)d_in[1];
    const float* wh = (const float*)d_in[2];
    float* out = (float*)d_out;
    float* ws  = (float*)d_ws;

    dim3 grid((WW / TW) * (HH / TH) * 8); // 16384, flattened for XCD remap
    dim3 block(256);

    // ping-pong: iter 0 -> ws, iter 1 -> out, ..., iter 7 -> out
    const float* src = x;
    for (int it = 0; it < 8; ++it) {
        float* dst = (it & 1) ? out : ws;
        gated_step<<<grid, block, 0, stream>>>(src, wg, wh, dst);
        src = dst;
    }
}

// Round 2
// 1553.631 us; speedup vs baseline: 4.5567x; 4.5567x over previous
//
#include <hip/hip_runtime.h>

// IterativeGatedConv2D: 8 iterations of
//   g  = circ_depthwise_conv7x7(h, Wg); ht = circ_depthwise_conv7x7(h, Wh)
//   h  = h + sigmoid(g) * (ht - h)
// Layout: (B=8, H=256, W=256, C=64) channels-last fp32.
//
// R5: FUSED single LDS sweep, TC=4 cols/thread, big tile.
//  - R4 post-mortem: two-pass @ 1 col = 196 ds_reads/thread -> LDS-pipe floor
//    ~121us/step; AND launch_bounds(256,4) capped unified regs at 128 ->
//    ~1.8GB/step scratch spills (WRITE_SIZE 15x). Both wrong.
//  - LDS-pipe arithmetic (5.8 cyc/ds_read_b32/CU): reads per output element
//    is the figure of merit. R3: 98/8 = 12.25 -> 61us floor. This kernel:
//    140/32 = 4.4 -> ~28us floor. VALU floor 42us, HBM ~45us.
//  - Tile (8+6)x(16+6)x64 fp32 = 78,848B. LDS caps occupancy at 2 blocks/CU
//    (2 waves/SIMD) REGARDLESS of VGPRs -> allocator has a free 256-reg
//    budget (launch_bounds(256,2) says so) -> ~215 live regs fit with zero
//    spills and zero AGPR-parking movs (the R0-R3 45%-VALUBusy tax).
//  - Block: 256 thr = 64 ch (lane c=tid&63) x 4 xi; thread computes 4 cols
//    x 8 rows. One barrier total; weights loaded during staging latency.
// R4b kept: XCD-aware remap, grid 4096 (%8==0, bijective): b = id&7 -> each
//    XCD works one batch image; halo re-reads resolve in its private L2.

#define HH 256
#define WW 256
#define CC 64
#define TH 8
#define TC 4
#define BW 16       // cols per block = 4 xi * TC
#define LH (TH + 6) // 14
#define LW (BW + 6) // 22

__global__ __launch_bounds__(256, 2) void gated_step(
    const float* __restrict__ src,
    const float* __restrict__ wg_g,
    const float* __restrict__ wh_g,
    float* __restrict__ dst)
{
    __shared__ float tile[LH * LW * CC]; // 78,848 B -> 2 blocks/CU

    const int tid = threadIdx.x;
    const int c   = tid & 63;
    const int xi  = tid >> 6;      // 0..3

    const int id  = (int)blockIdx.x;
    const int nid = ((id & 7) << 9) | (id >> 3); // XCD-contiguous remap
    const int bx  = nid & 15;
    const int by  = (nid >> 4) & 31;
    const int b   = nid >> 9;      // == id & 7

    const int x0 = bx * BW;
    const int y0 = by * TH;

    // ---- per-lane weights (channel c), 2x49 taps, in registers ----
    float wg[49], wh[49];
    #pragma unroll
    for (int t = 0; t < 49; ++t) wg[t] = wg_g[c * 49 + t];
    #pragma unroll
    for (int t = 0; t < 49; ++t) wh[t] = wh_g[c * 49 + t];

    // ---- stage input tile with circular wrap, float4-vectorized ----
    const float4* __restrict__ src4 = reinterpret_cast<const float4*>(src);
    const int total4 = LH * LW * (CC / 4); // 4928
    for (int k = tid; k < total4; k += 256) {
        int c4 = k & 15;
        int sp = k >> 4;              // 0..307
        int jx = sp % LW;
        int iy = sp / LW;
        int gy = (y0 + iy - 3) & 255;
        int gx = (x0 + jx - 3) & 255;
        float4 val = src4[((((b << 8) + gy) << 8) + gx) * (CC / 4) + c4];
        *reinterpret_cast<float4*>(&tile[(sp << 6) + (c4 << 2)]) = val;
    }
    __syncthreads();

    // ---- fused sliding-window compute: 4 cols x 8 rows per thread ----
    const float* tbase = &tile[(xi * TC) * CC + c];

    float accg[TC][TH], acch[TC][TH], ctr[TC][TH];
    #pragma unroll
    for (int q = 0; q < TC; ++q)
        #pragma unroll
        for (int r = 0; r < TH; ++r) { accg[q][r] = 0.0f; acch[q][r] = 0.0f; }

    #pragma unroll
    for (int iy = 0; iy < LH; ++iy) {
        float v[TC + 6]; // 10 taps cover 4 output cols
        #pragma unroll
        for (int j = 0; j < TC + 6; ++j)
            v[j] = tbase[(iy * LW + j) * CC];
        if (iy >= 3 && iy < 3 + TH) {
            #pragma unroll
            for (int q = 0; q < TC; ++q) ctr[q][iy - 3] = v[q + 3]; // center tap
        }
        #pragma unroll
        for (int r = 0; r < TH; ++r) {
            const int i = r + 6 - iy;   // kernel row index
            if (i >= 0 && i <= 6) {
                #pragma unroll
                for (int jv = 0; jv < 7; ++jv) {
                    // kernel col j = 6 - jv pairs with tap v[q + jv]
                    const float a = wg[i * 7 + (6 - jv)];
                    const float h = wh[i * 7 + (6 - jv)];
                    #pragma unroll
                    for (int q = 0; q < TC; ++q) {
                        accg[q][r] = fmaf(a, v[q + jv], accg[q][r]);
                        acch[q][r] = fmaf(h, v[q + jv], acch[q][r]);
                    }
                }
            }
        }
    }

    // ---- epilogue: sigmoid gate + blend, coalesced store ----
    #pragma unroll
    for (int r = 0; r < TH; ++r) {
        const int gy = y0 + r;
        #pragma unroll
        for (int q = 0; q < TC; ++q) {
            float e  = __expf(-accg[q][r]);
            float z  = __builtin_amdgcn_rcpf(1.0f + e);
            float hn = fmaf(z, acch[q][r] - ctr[q][r], ctr[q][r]);
            const int gx = x0 + xi * TC + q;
            dst[((((b << 8) + gy) << 8) + gx) * CC + c] = hn;
        }
    }
}

extern "C" void kernel_launch(void* const* d_in, const int* in_sizes, int n_in,
                              void* d_out, int out_size, void* d_ws, size_t ws_size,
                              hipStream_t stream) {
    const float* x  = (const float*)d_in[0];
    const float* wg = (const float*)d_in[1];
    const float* wh = (const float*)d_in[2];
    float* out = (float*)d_out;
    float* ws  = (float*)d_ws;

    dim3 grid((WW / BW) * (HH / TH) * 8); // 16*32*8 = 4096, flat for XCD remap
    dim3 block(256);

    // ping-pong: iter 0 -> ws, iter 1 -> out, ..., iter 7 -> out
    const float* src = x;
    for (int it = 0; it < 8; ++it) {
        float* dst = (it & 1) ? out : ws;
        gated_step<<<grid, block, 0, stream>>>(src, wg, wh, dst);
        src = dst;
    }
}

// Round 3
// 1167.414 us; speedup vs baseline: 6.0642x; 1.3308x over previous
//
#include <hip/hip_runtime.h>

// IterativeGatedConv2D: 8 iterations of
//   g  = circ_depthwise_conv7x7(h, Wg); ht = circ_depthwise_conv7x7(h, Wh)
//   h  = h + sigmoid(g) * (ht - h)
// Layout: (B=8, H=256, W=256, C=64) channels-last fp32.
//
// R6: WAVE-PER-CHANNEL, SGPR gate weights.
//  - R5 post-mortem: lane-per-channel keeps 98 weights in the vector file;
//    live ~215 > 124 arch VGPRs -> AGPR parking -> 2.5x VALU bloat (measured
//    15.8K cyc/wave vs 6.3K real FMA), at only 8 waves/CU. Structural fix:
//    weights must leave the vector file.
//  - Block = 4 waves = 4 channels; lane = x (2 output cols), 8 output rows.
//    Gate weights -> SGPRs via readfirstlane (v_fmac v,s,v reads 1 SGPR: ok).
//    Hidden weights -> 49 VGPRs broadcast-read from LDS (98 SGPRs + misc
//    would exceed the 102/wave SGPR cap).
//    Per-lane live: 49 wh + 32 acc + 8 taps + ~15 addr ~= 110 <= 128
//    -> __launch_bounds__(256,4), 4 blocks/CU, 16 waves/CU, zero parking.
//  - LDS per-channel planes [14][134]: tap reads = 4x ds_read_b64/row,
//    8B lane stride, conflict-free. 56 b64 / 16 outputs.
//  - Channels-last global vs per-channel compute: staging reads are 16B/lane
//    (L2-gathered; the 16 channel-group blocks of one tile are made adjacent
//    on one XCD by the remap, so lines are fully consumed in L2). Stores are
//    re-coalesced to float4 via an LDS transpose (reuses the tile region).
//  - Tripwires: WRITE_SIZE != 131072 KB => spills or failed write-merge;
//    SGPR_Count < ~90 => weights didn't scalarize.

#define HH 256
#define WW 256
#define CC 64
#define TH 8              // output rows per block
#define BC 128            // output cols per block (2 per lane)
#define LHT (TH + 6)      // 14
#define LWT (BC + 6)      // 134
#define PLANE (LHT * LWT) // 1876 floats per channel plane
#define WOFF (4 * PLANE)  // 7504: hidden-weight staging area
#define LDS_FLOATS (WOFF + 196)

__global__ __launch_bounds__(256, 4) void gated_step(
    const float* __restrict__ src,
    const float* __restrict__ wg_g,
    const float* __restrict__ wh_g,
    float* __restrict__ dst)
{
    __shared__ float lds[LDS_FLOATS]; // 30,800 B

    const int tid = threadIdx.x;
    const int x   = tid & 63;                                   // lane = x pair
    const int w   = __builtin_amdgcn_readfirstlane(tid >> 6);   // wave id 0..3

    // XCD remap: 8192 blocks, chunk of 1024 per XCD = one batch image.
    // Within a chunk, cg is the fastest bit-field -> the 16 channel-group
    // blocks of one spatial tile are adjacent on the same XCD (L2 sharing).
    const int id  = (int)blockIdx.x;
    const int nid = ((id & 7) << 10) | (id >> 3);
    const int cg  = nid & 15;         // channel group: channels 4cg..4cg+3
    const int xs  = (nid >> 4) & 1;
    const int ys  = (nid >> 5) & 31;
    const int b   = nid >> 10;        // == id & 7
    const int x0  = xs * BC;
    const int y0  = ys * TH;
    const int ch  = (cg << 2) | w;    // wave-uniform channel

    // ---- gate weights -> SGPRs (forced scalar via readfirstlane) ----
    float sw[49];
    #pragma unroll
    for (int t = 0; t < 49; ++t)
        sw[t] = __int_as_float(
            __builtin_amdgcn_readfirstlane(__float_as_int(wg_g[ch * 49 + t])));

    // ---- stage input tile into 4 channel planes + hidden weights ----
    const float4* __restrict__ src4 = reinterpret_cast<const float4*>(src);
    for (int k = tid; k < PLANE; k += 256) {
        int col = k % LWT;
        int row = k / LWT;
        int gy = (y0 + row - 3) & 255;
        int gx = (x0 + col - 3) & 255;
        float4 v4 = src4[((((b << 8) + gy) << 8) + gx) * 16 + cg];
        lds[0 * PLANE + k] = v4.x;
        lds[1 * PLANE + k] = v4.y;
        lds[2 * PLANE + k] = v4.z;
        lds[3 * PLANE + k] = v4.w;
    }
    if (tid < 196) lds[WOFF + tid] = wh_g[cg * 196 + tid]; // 4 ch x 49
    __syncthreads();

    // ---- hidden weights -> VGPRs (LDS broadcast, wave-uniform addr) ----
    float wh[49];
    #pragma unroll
    for (int t = 0; t < 49; ++t) wh[t] = lds[WOFF + w * 49 + t];

    // ---- fused sliding-window conv: 2 cols x 8 rows per lane ----
    const float* plane = &lds[w * PLANE];
    float accg[2][TH], acch[2][TH];
    #pragma unroll
    for (int r = 0; r < TH; ++r) {
        accg[0][r] = 0.0f; accg[1][r] = 0.0f;
        acch[0][r] = 0.0f; acch[1][r] = 0.0f;
    }

    #pragma unroll
    for (int iy = 0; iy < LHT; ++iy) {
        float v[8]; // taps for cols 2x .. 2x+7
        const float* rowp = plane + iy * LWT + 2 * x;
        #pragma unroll
        for (int m = 0; m < 4; ++m) {
            float2 t2 = *reinterpret_cast<const float2*>(rowp + 2 * m);
            v[2 * m]     = t2.x;
            v[2 * m + 1] = t2.y;
        }
        #pragma unroll
        for (int r = 0; r < TH; ++r) {
            const int i = r + 6 - iy;          // kernel row
            if (i >= 0 && i <= 6) {
                #pragma unroll
                for (int jv = 0; jv < 7; ++jv) {
                    const float a = sw[i * 7 + (6 - jv)]; // SGPR operand
                    const float h = wh[i * 7 + (6 - jv)];
                    accg[0][r] = fmaf(a, v[jv],     accg[0][r]);
                    acch[0][r] = fmaf(h, v[jv],     acch[0][r]);
                    accg[1][r] = fmaf(a, v[jv + 1], accg[1][r]);
                    acch[1][r] = fmaf(h, v[jv + 1], acch[1][r]);
                }
            }
        }
    }

    // ---- epilogue: sigmoid gate + blend (ctr re-read from tile) ----
    float hn[2][TH];
    #pragma unroll
    for (int r = 0; r < TH; ++r) {
        float c0 = plane[(r + 3) * LWT + 2 * x + 3];
        float c1 = plane[(r + 3) * LWT + 2 * x + 4];
        float e0 = __expf(-accg[0][r]);
        float e1 = __expf(-accg[1][r]);
        float z0 = __builtin_amdgcn_rcpf(1.0f + e0);
        float z1 = __builtin_amdgcn_rcpf(1.0f + e1);
        hn[0][r] = fmaf(z0, acch[0][r] - c0, c0);
        hn[1][r] = fmaf(z1, acch[1][r] - c1, c1);
    }
    __syncthreads(); // all waves done reading tile

    // ---- LDS transpose: [4 ch][8 r][128 c] into plane region ----
    #pragma unroll
    for (int r = 0; r < TH; ++r) {
        float2 p; p.x = hn[0][r]; p.y = hn[1][r];
        *reinterpret_cast<float2*>(&lds[w * 1024 + r * 128 + 2 * x]) = p;
    }
    __syncthreads();

    // ---- coalesced float4 store: thread -> (row, col), 4 channels ----
    float4* __restrict__ dst4 = reinterpret_cast<float4*>(dst);
    #pragma unroll
    for (int k2 = 0; k2 < 4; ++k2) {
        int pos = tid + k2 * 256;      // 0..1023
        int c2  = pos & 127;
        int r   = pos >> 7;
        float4 o;
        o.x = lds[0 * 1024 + r * 128 + c2];
        o.y = lds[1 * 1024 + r * 128 + c2];
        o.z = lds[2 * 1024 + r * 128 + c2];
        o.w = lds[3 * 1024 + r * 128 + c2];
        dst4[((((b << 8) + (y0 + r)) << 8) + (x0 + c2)) * 16 + cg] = o;
    }
}

extern "C" void kernel_launch(void* const* d_in, const int* in_sizes, int n_in,
                              void* d_out, int out_size, void* d_ws, size_t ws_size,
                              hipStream_t stream) {
    const float* x  = (const float*)d_in[0];
    const float* wg = (const float*)d_in[1];
    const float* wh = (const float*)d_in[2];
    float* out = (float*)d_out;
    float* ws  = (float*)d_ws;

    dim3 grid(8 * 32 * 2 * 16); // 8192: b x ystrip x xstrip x channel-group
    dim3 block(256);

    const float* src = x;
    for (int it = 0; it < 8; ++it) {
        float* dst = (it & 1) ? out : ws;
        gated_step<<<grid, block, 0, stream>>>(src, wg, wh, dst);
        src = dst;
    }
}